// Round 6
// baseline (88.930 us; speedup 1.0000x reference)
//
#include <hip/hip_runtime.h>
#include <math.h>

#define BATCH 65536
#define XPER  576              // 24*24 floats per image
#define NBLK  512              // == 2 blocks/CU * 256 CUs (co-resident by LDS)
#define EPB   128              // images per block
#define GPI   16               // images per tile
#define ITERS (EPB / GPI)      // 8
#define TILEF (GPI * XPER)     // 9216 floats per tile

// ws layout (zeroed by 64-byte memset node):
//   f32 [0..3] sum_z, [4..7] sum_z2 ; u32 [8] arrive cnt, [9] release flag

__device__ __forceinline__ void gload16(const float* g, float* l) {
    __builtin_amdgcn_global_load_lds(
        (__attribute__((address_space(1))) void*)(g),
        (__attribute__((address_space(3))) void*)(l),
        16, 0, 0);
}

// ---------------------------------------------------------------- K1
__global__ __launch_bounds__(256, 2) void circuit_kernel(
        const float* __restrict__ x, const float* __restrict__ params,
        const float* __restrict__ gamma, const float* __restrict__ beta,
        float* __restrict__ out, float* __restrict__ ws) {
    __shared__ float sx[2][TILEF];     // 73728 B double-buffered tile
    __shared__ float sU[512];          // Ur row-major, then Ui
    __shared__ float sg[48];           // 8 gates x {c,s,epr,epi,emr,emi}
    __shared__ float sv[256];          // per-wave pooled-v strips (4 x 64)
    __shared__ float spart[8];
    __shared__ float sstat[8];
    __shared__ float scoef[8];

    float* accums = ws;                          // 8 floats
    unsigned* cnt  = (unsigned*)(ws + 8);
    unsigned* flag = (unsigned*)(ws + 9);

    const int t    = threadIdx.x;
    const int wid  = t >> 6;           // wave id (0..3)
    const int lane = t & 63;
    const int e    = t >> 4;           // image within tile (0..15)
    const int le   = e & 3;            // image within wave (0..3)
    const int p    = t & 15;           // pool cell == state row

    const size_t base = (size_t)blockIdx.x * EPB;

    // ---- stage tile 0 (async, fires before the trig/fold work)
    {
        const float* src = x + base * XPER + wid * 2304 + lane * 4;
        float* dst = &sx[0][wid * 2304];
#pragma unroll
        for (int j = 0; j < 9; ++j) gload16(src + j * 256, dst + j * 256);
    }

    if (t < 8) {
        spart[t] = 0.0f;
        float phi   = params[t * 3 + 0];
        float theta = params[t * 3 + 1];
        float omega = params[t * 3 + 2];
        float apo = 0.5f * (phi + omega), amo = 0.5f * (phi - omega);
        sg[t * 6 + 0] = cosf(0.5f * theta);
        sg[t * 6 + 1] = sinf(0.5f * theta);
        sg[t * 6 + 2] = cosf(apo);           // epr (ep = e^{-i(phi+omega)/2})
        sg[t * 6 + 3] = -sinf(apo);          // epi
        sg[t * 6 + 4] = cosf(amo);           // emr (em = e^{+i(phi-omega)/2})
        sg[t * 6 + 5] = sinf(amo);           // emi
    }
    __syncthreads();

    // ---- fold circuit into U (lane j owns column j of M; state' = M state)
    if (t < 16) {
        const int j = t;
        float Mr[16], Mi[16];
#pragma unroll
        for (int i = 0; i < 16; ++i) { Mr[i] = (i == j) ? 1.0f : 0.0f; Mi[i] = 0.0f; }
#pragma unroll
        for (int l = 0; l < 2; ++l) {
#pragma unroll
            for (int w = 0; w < 4; ++w) {
                const int g = l * 4 + w;
                float c   = sg[g * 6 + 0], s   = sg[g * 6 + 1];
                float epr = sg[g * 6 + 2], epi = sg[g * 6 + 3];
                float emr = sg[g * 6 + 4], emi = sg[g * 6 + 5];
                float m00r =  epr * c, m00i =  epi * c;
                float m01r = -emr * s, m01i = -emi * s;
                float m10r =  emr * s, m10i = -emi * s;
                float m11r =  epr * c, m11i = -epi * c;
                const int mask = 1 << (3 - w);
#pragma unroll
                for (int i = 0; i < 16; ++i) {
                    if (i & mask) continue;
                    int i1 = i | mask;
                    float r0 = Mr[i],  q0 = Mi[i];
                    float r1 = Mr[i1], q1 = Mi[i1];
                    Mr[i]  = m00r * r0 - m00i * q0 + m01r * r1 - m01i * q1;
                    Mi[i]  = m00r * q0 + m00i * r0 + m01r * q1 + m01i * r1;
                    Mr[i1] = m10r * r0 - m10i * q0 + m11r * r1 - m11i * q1;
                    Mi[i1] = m10r * q0 + m10i * r0 + m11r * q1 + m11i * r1;
                }
            }
            const int rr = (l % 3) + 1;
#pragma unroll
            for (int w = 0; w < 4; ++w) {
                int tq = (w + rr) & 3;
                int cb = 3 - w, tb = 3 - tq;
#pragma unroll
                for (int i = 0; i < 16; ++i) {
                    int pi = i ^ (((i >> cb) & 1) << tb);
                    if (pi > i) {
                        float tr = Mr[i]; Mr[i] = Mr[pi]; Mr[pi] = tr;
                        float ti = Mi[i]; Mi[i] = Mi[pi]; Mi[pi] = ti;
                    }
                }
            }
        }
#pragma unroll
        for (int i = 0; i < 16; ++i) {
            sU[i * 16 + j]       = Mr[i];
            sU[256 + i * 16 + j] = Mi[i];
        }
    }
    __syncthreads();

    // ---- U row p -> registers (float4 LDS reads, once)
    float ur[16], ui[16];
    {
        const float4* u4 = (const float4*)(sU + p * 16);
        const float4* v4 = (const float4*)(sU + 256 + p * 16);
#pragma unroll
        for (int q = 0; q < 4; ++q) {
            float4 a = u4[q], b = v4[q];
            ur[4 * q + 0] = a.x; ur[4 * q + 1] = a.y; ur[4 * q + 2] = a.z; ur[4 * q + 3] = a.w;
            ui[4 * q + 0] = b.x; ui[4 * q + 1] = b.y; ui[4 * q + 2] = b.z; ui[4 * q + 3] = b.w;
        }
    }

    // writer lane -> output channel (z_w lives at group-lane 1<<(3-w))
    int c = -1;
    if      (p == 8) c = 0;
    else if (p == 4) c = 1;
    else if (p == 2) c = 2;
    else if (p == 1) c = 3;

    const int r0 = (e + (p >> 2)) % 6;      // per-lane row rotation (bank spread)
    float zbuf[ITERS];
    float accz = 0.0f, accz2 = 0.0f;

    // ---- main pipeline: counted vmcnt, raw barriers, loads span barriers
#pragma unroll
    for (int it = 0; it < ITERS; ++it) {
        if (it + 1 < ITERS) {
            const float* src = x + (base + (size_t)(it + 1) * GPI) * XPER
                                 + wid * 2304 + lane * 4;
            float* dst = &sx[(it + 1) & 1][wid * 2304];
#pragma unroll
            for (int j = 0; j < 9; ++j) gload16(src + j * 256, dst + j * 256);
            asm volatile("s_waitcnt vmcnt(9)" ::: "memory");  // tile it done
        } else {
            asm volatile("s_waitcnt vmcnt(0)" ::: "memory");
        }
        __builtin_amdgcn_s_barrier();

        // ---- 6x6 average pool, rows read in rotated order (bank spread)
        const float* bs = sx[it & 1] + e * XPER + (p >> 2) * 144 + (p & 3) * 6;
        float sum = 0.0f;
#pragma unroll
        for (int i = 0; i < 6; ++i) {
            int row = r0 + i; if (row >= 6) row -= 6;
            const float2* rp = (const float2*)(bs + row * 24);
            float2 a2 = rp[0], b2 = rp[1], d2 = rp[2];
            sum += a2.x + a2.y + b2.x + b2.y + d2.x + d2.y;
        }
        float v = sum * (1.0f / 36.0f);

        // ---- per-wave LDS strip: write v, broadcast-read whole vector.
        // All 16 lanes of an image group are in THIS wave; DS ops are
        // in-order per wave, so no barrier is needed.
        sv[wid * 64 + le * 16 + p] = v;
        float vv[16];
        {
            const float4* vb = (const float4*)(sv + wid * 64 + le * 16);
#pragma unroll
            for (int q = 0; q < 4; ++q) {
                float4 a = vb[q];
                vv[4 * q + 0] = a.x; vv[4 * q + 1] = a.y;
                vv[4 * q + 2] = a.z; vv[4 * q + 3] = a.w;
            }
        }
        float n2 = 0.0f, sr = 0.0f, si = 0.0f;
#pragma unroll
        for (int j = 0; j < 16; ++j) {
            n2 = fmaf(vv[j], vv[j], n2);
            sr = fmaf(ur[j], vv[j], sr);
            si = fmaf(ui[j], vv[j], si);
        }
        float prob = (sr * sr + si * si) / n2;

        // ---- 16-pt Walsh-Hadamard across the 16-lane group
        float a = prob, o;
        o = __shfl_xor(a, 1); a = (t & 1) ? (o - a) : (a + o);
        o = __shfl_xor(a, 2); a = (t & 2) ? (o - a) : (a + o);
        o = __shfl_xor(a, 4); a = (t & 4) ? (o - a) : (a + o);
        o = __shfl_xor(a, 8); a = (t & 8) ? (o - a) : (a + o);

        zbuf[it] = a;
        if (c >= 0) { accz += a; accz2 += a * a; }

        __builtin_amdgcn_s_barrier();   // all reads of buf[it&1] done
    }

    // ---- block-level BN partials -> global accumulators
    if (c >= 0) {
        atomicAdd(&spart[c], accz);
        atomicAdd(&spart[4 + c], accz2);
    }
    __syncthreads();
    if (t < 8) atomicAdd(&accums[t], spart[t]);
    __syncthreads();                    // drains vmcnt -> adds complete

    // ---- grid barrier (all NBLK blocks co-resident: 2/CU by LDS)
    if (t == 0) {
        __threadfence();
        unsigned old = atomicAdd(cnt, 1u);
        if (old == NBLK - 1) {
            __threadfence();
            atomicExch(flag, 1u);
        } else {
            while (atomicAdd(flag, 0u) == 0u) __builtin_amdgcn_s_sleep(8);
        }
    }
    __syncthreads();

    // ---- read global stats (device-coherent atomic reads), compute coefs
    if (t < 8) sstat[t] = atomicAdd(&accums[t], 0.0f);
    __syncthreads();
    if (t < 4) {
        float mu  = sstat[t] * (1.0f / BATCH);
        float var = sstat[4 + t] * (1.0f / BATCH) - mu * mu;
        float a = gamma[t] * rsqrtf(var + 1e-5f);
        scoef[t]     = a;
        scoef[4 + t] = beta[t] - mu * a;
    }
    __syncthreads();

    // ---- apply BN to reg-resident z, single store pass
    if (c >= 0) {
        float A = scoef[c], B = scoef[4 + c];
#pragma unroll
        for (int it = 0; it < ITERS; ++it)
            out[(base + (size_t)it * GPI + e) * 4 + c] = fmaf(zbuf[it], A, B);
    }
}

extern "C" void kernel_launch(void* const* d_in, const int* in_sizes, int n_in,
                              void* d_out, int out_size, void* d_ws, size_t ws_size,
                              hipStream_t stream) {
    const float* x      = (const float*)d_in[0];
    const float* params = (const float*)d_in[1];
    const float* gamma  = (const float*)d_in[2];
    const float* beta   = (const float*)d_in[3];
    float* out = (float*)d_out;
    float* ws  = (float*)d_ws;

    hipMemsetAsync(ws, 0, 64, stream);   // zero accumulators + barrier words
    hipLaunchKernelGGL(circuit_kernel, dim3(NBLK), dim3(256), 0, stream,
                       x, params, gamma, beta, out, ws);
}

// Round 7
// 40.662 us; speedup vs baseline: 2.1871x; 2.1871x over previous
//
#include <hip/hip_runtime.h>
#include <math.h>

#define BATCH 65536
#define XPER  576               // 24*24 floats per image
#define NBLK  512
#define EPB   128               // images per block
#define WPB   4                 // waves per block
#define IPW   (EPB / WPB)       // 32 images per wave
#define CHUNK 4                 // images per wave-chunk
#define NCH   (IPW / CHUNK)     // 8 chunks per wave
#define CHF   (CHUNK * XPER)    // 2304 floats per chunk buffer

// ws float layout: [0..3] sum_z, [4..7] sum_z2   (zeroed by memset node)

__device__ __forceinline__ void gload16(const float* g, float* l) {
    __builtin_amdgcn_global_load_lds(
        (__attribute__((address_space(1))) void*)(g),
        (__attribute__((address_space(3))) void*)(l),
        16, 0, 0);
}

// ---------------------------------------------------------------- K1
// Wave-private double-buffered pipeline: NO s_barrier in the main loop.
// Each wave stages its own 4-image chunk with global_load_lds and
// self-syncs with counted vmcnt; DS ops are in-order per wave.
__global__ __launch_bounds__(256, 2) void circuit_kernel(
        const float* __restrict__ x, const float* __restrict__ params,
        float* __restrict__ out, float* __restrict__ accums) {
    __shared__ float sx[WPB][2][CHF];  // 73728 B: per-wave double buffers
    __shared__ float sU[512];          // Ur row-major, then Ui
    __shared__ float sg[48];           // 8 gates x {c,s,epr,epi,emr,emi}
    __shared__ float sv[256];          // per-wave pooled-v strips
    __shared__ float spart[8];

    const int t    = threadIdx.x;
    const int wid  = t >> 6;           // wave id (0..3)
    const int lane = t & 63;
    const int e    = lane >> 4;        // image within chunk (0..3)
    const int p    = lane & 15;        // pool cell == state row

    const size_t ibase = (size_t)blockIdx.x * EPB + (size_t)wid * IPW;

    // ---- prefetch chunk 0 into this wave's buffer 0
    {
        const float* src = x + ibase * XPER + lane * 4;
        float* dst = &sx[wid][0][0];
#pragma unroll
        for (int j = 0; j < 9; ++j) gload16(src + j * 256, dst + j * 256);
    }

    if (t < 8) {
        spart[t] = 0.0f;
        float phi   = params[t * 3 + 0];
        float theta = params[t * 3 + 1];
        float omega = params[t * 3 + 2];
        float apo = 0.5f * (phi + omega), amo = 0.5f * (phi - omega);
        sg[t * 6 + 0] = cosf(0.5f * theta);
        sg[t * 6 + 1] = sinf(0.5f * theta);
        sg[t * 6 + 2] = cosf(apo);           // epr (ep = e^{-i(phi+omega)/2})
        sg[t * 6 + 3] = -sinf(apo);          // epi
        sg[t * 6 + 4] = cosf(amo);           // emr (em = e^{+i(phi-omega)/2})
        sg[t * 6 + 5] = sinf(amo);           // emi
    }
    __syncthreads();

    // ---- fold circuit into U (lane j owns column j of M; state' = M state)
    if (t < 16) {
        const int j = t;
        float Mr[16], Mi[16];
#pragma unroll
        for (int i = 0; i < 16; ++i) { Mr[i] = (i == j) ? 1.0f : 0.0f; Mi[i] = 0.0f; }
#pragma unroll
        for (int l = 0; l < 2; ++l) {
#pragma unroll
            for (int w = 0; w < 4; ++w) {
                const int g = l * 4 + w;
                float c   = sg[g * 6 + 0], s   = sg[g * 6 + 1];
                float epr = sg[g * 6 + 2], epi = sg[g * 6 + 3];
                float emr = sg[g * 6 + 4], emi = sg[g * 6 + 5];
                float m00r =  epr * c, m00i =  epi * c;
                float m01r = -emr * s, m01i = -emi * s;
                float m10r =  emr * s, m10i = -emi * s;
                float m11r =  epr * c, m11i = -epi * c;
                const int mask = 1 << (3 - w);
#pragma unroll
                for (int i = 0; i < 16; ++i) {
                    if (i & mask) continue;
                    int i1 = i | mask;
                    float r0 = Mr[i],  q0 = Mi[i];
                    float r1 = Mr[i1], q1 = Mi[i1];
                    Mr[i]  = m00r * r0 - m00i * q0 + m01r * r1 - m01i * q1;
                    Mi[i]  = m00r * q0 + m00i * r0 + m01r * q1 + m01i * r1;
                    Mr[i1] = m10r * r0 - m10i * q0 + m11r * r1 - m11i * q1;
                    Mi[i1] = m10r * q0 + m10i * r0 + m11r * q1 + m11i * r1;
                }
            }
            const int rr = (l % 3) + 1;
#pragma unroll
            for (int w = 0; w < 4; ++w) {
                int tq = (w + rr) & 3;
                int cb = 3 - w, tb = 3 - tq;
#pragma unroll
                for (int i = 0; i < 16; ++i) {
                    int pi = i ^ (((i >> cb) & 1) << tb);
                    if (pi > i) {
                        float tr = Mr[i]; Mr[i] = Mr[pi]; Mr[pi] = tr;
                        float ti = Mi[i]; Mi[i] = Mi[pi]; Mi[pi] = ti;
                    }
                }
            }
        }
#pragma unroll
        for (int i = 0; i < 16; ++i) {
            sU[i * 16 + j]       = Mr[i];
            sU[256 + i * 16 + j] = Mi[i];
        }
    }
    __syncthreads();

    // ---- U row p -> registers (float4 LDS reads, once)
    float ur[16], ui[16];
    {
        const float4* u4 = (const float4*)(sU + p * 16);
        const float4* v4 = (const float4*)(sU + 256 + p * 16);
#pragma unroll
        for (int q = 0; q < 4; ++q) {
            float4 a = u4[q], b = v4[q];
            ur[4 * q + 0] = a.x; ur[4 * q + 1] = a.y; ur[4 * q + 2] = a.z; ur[4 * q + 3] = a.w;
            ui[4 * q + 0] = b.x; ui[4 * q + 1] = b.y; ui[4 * q + 2] = b.z; ui[4 * q + 3] = b.w;
        }
    }
    // ---- no more barriers until epilogue: waves run decoupled ----

    // writer lane -> output channel (z_w lives at group-lane 1<<(3-w))
    int c = -1;
    if      (p == 8) c = 0;
    else if (p == 4) c = 1;
    else if (p == 2) c = 2;
    else if (p == 1) c = 3;

    const int r0 = (e + (p >> 2)) % 6;   // per-lane row rotation (bank spread)
    float zbuf[NCH];
    float accz = 0.0f, accz2 = 0.0f;

#pragma unroll
    for (int ch = 0; ch < NCH; ++ch) {
        if (ch + 1 < NCH) {
            const float* src = x + (ibase + (size_t)(ch + 1) * CHUNK) * XPER + lane * 4;
            float* dst = &sx[wid][(ch + 1) & 1][0];
#pragma unroll
            for (int j = 0; j < 9; ++j) gload16(src + j * 256, dst + j * 256);
            asm volatile("s_waitcnt vmcnt(9)" ::: "memory");  // chunk ch landed
        } else {
            asm volatile("s_waitcnt vmcnt(0)" ::: "memory");
        }

        // ---- 6x6 average pool, rows in rotated order (bank spread)
        const float* bs = &sx[wid][ch & 1][0] + e * XPER + (p >> 2) * 144 + (p & 3) * 6;
        float sum = 0.0f;
#pragma unroll
        for (int i = 0; i < 6; ++i) {
            int row = r0 + i; if (row >= 6) row -= 6;
            const float2* rp = (const float2*)(bs + row * 24);
            float2 a2 = rp[0], b2 = rp[1], d2 = rp[2];
            sum += a2.x + a2.y + b2.x + b2.y + d2.x + d2.y;
        }
        float v = sum * (1.0f / 36.0f);

        // ---- per-wave strip: write v, broadcast-read the image's 16 v's.
        // Wave-private region + DS in-order per wave => no sync needed.
        sv[wid * 64 + e * 16 + p] = v;
        float vv[16];
        {
            const float4* vb = (const float4*)(sv + wid * 64 + e * 16);
#pragma unroll
            for (int q = 0; q < 4; ++q) {
                float4 a = vb[q];
                vv[4 * q + 0] = a.x; vv[4 * q + 1] = a.y;
                vv[4 * q + 2] = a.z; vv[4 * q + 3] = a.w;
            }
        }
        float n2 = 0.0f, sr = 0.0f, si = 0.0f;
#pragma unroll
        for (int j = 0; j < 16; ++j) {
            n2 = fmaf(vv[j], vv[j], n2);
            sr = fmaf(ur[j], vv[j], sr);
            si = fmaf(ui[j], vv[j], si);
        }
        float prob = (sr * sr + si * si) / n2;

        // ---- 16-pt Walsh-Hadamard across the 16-lane group
        float a = prob, o;
        o = __shfl_xor(a, 1); a = (t & 1) ? (o - a) : (a + o);
        o = __shfl_xor(a, 2); a = (t & 2) ? (o - a) : (a + o);
        o = __shfl_xor(a, 4); a = (t & 4) ? (o - a) : (a + o);
        o = __shfl_xor(a, 8); a = (t & 8) ? (o - a) : (a + o);

        zbuf[ch] = a;
        if (c >= 0) { accz += a; accz2 += a * a; }
    }

    // ---- epilogue: stores out of the loop (keeps vmcnt counts exact)
    if (c >= 0) {
#pragma unroll
        for (int ch = 0; ch < NCH; ++ch)
            out[(ibase + (size_t)ch * CHUNK + e) * 4 + c] = zbuf[ch];
        atomicAdd(&spart[c], accz);
        atomicAdd(&spart[4 + c], accz2);
    }
    __syncthreads();
    if (t < 8) atomicAdd(&accums[t], spart[t]);
}

// ---------------------------------------------------------------- K2
__global__ __launch_bounds__(256) void bn_apply(float* __restrict__ out,
                                                const float* __restrict__ accums,
                                                const float* __restrict__ gamma,
                                                const float* __restrict__ beta) {
    __shared__ float sc[8];
    const int t = threadIdx.x;
    if (t < 4) {
        float mu  = accums[t] * (1.0f / BATCH);
        float var = accums[4 + t] * (1.0f / BATCH) - mu * mu;
        float a = gamma[t] * rsqrtf(var + 1e-5f);
        sc[t]     = a;
        sc[4 + t] = beta[t] - mu * a;
    }
    __syncthreads();
    int i = blockIdx.x * 256 + t;   // one float4 (one image) each
    float4 z = ((float4*)out)[i];
    z.x = fmaf(z.x, sc[0], sc[4]);
    z.y = fmaf(z.y, sc[1], sc[5]);
    z.z = fmaf(z.z, sc[2], sc[6]);
    z.w = fmaf(z.w, sc[3], sc[7]);
    ((float4*)out)[i] = z;
}

extern "C" void kernel_launch(void* const* d_in, const int* in_sizes, int n_in,
                              void* d_out, int out_size, void* d_ws, size_t ws_size,
                              hipStream_t stream) {
    const float* x      = (const float*)d_in[0];
    const float* params = (const float*)d_in[1];
    const float* gamma  = (const float*)d_in[2];
    const float* beta   = (const float*)d_in[3];
    float* out = (float*)d_out;
    float* ws  = (float*)d_ws;

    hipMemsetAsync(ws, 0, 32, stream);   // zero BN accumulators
    hipLaunchKernelGGL(circuit_kernel, dim3(NBLK), dim3(256), 0, stream,
                       x, params, out, ws);
    hipLaunchKernelGGL(bn_apply, dim3(BATCH / 256), dim3(256), 0, stream,
                       out, ws, gamma, beta);
}

// Round 8
// 40.505 us; speedup vs baseline: 2.1955x; 1.0039x over previous
//
#include <hip/hip_runtime.h>
#include <math.h>

#define BATCH 65536
#define XPER  576               // 24*24 floats per image
#define NBLK  512
#define EPB   128               // images per block
#define WPB   4                 // waves per block
#define IPW   (EPB / WPB)       // 32 images per wave
#define CHUNK 4                 // images per wave-chunk
#define NCH   (IPW / CHUNK)     // 8 chunks per wave
#define CHF   (CHUNK * XPER)    // 2304 floats per chunk buffer

// ws float layout: [0..3] sum_z, [4..7] sum_z2   (zeroed by memset node)

// LDS chunk layout: cell-PAIR major.  pair q = e*8 + prow*2 + P  (P = pc>>1)
//   float index Lf = q*72 + r*12 + cc   (r = row within cell 0..5, cc = 0..11)
// Every 4-float group of this layout is 4 contiguous global floats, so
// global_load_lds (16B) stages it with per-lane swizzled SOURCE addresses.

__device__ __forceinline__ void gload16(const float* g, float* l) {
    __builtin_amdgcn_global_load_lds(
        (__attribute__((address_space(1))) void*)(g),
        (__attribute__((address_space(3))) void*)(l),
        16, 0, 0);
}

// ---------------------------------------------------------------- K1
// Wave-private double-buffered pipeline, no in-loop barriers.
// Pool reads are 9 aligned conflict-spread ds_read_b128 per lane.
__global__ __launch_bounds__(256, 2) void circuit_kernel(
        const float* __restrict__ x, const float* __restrict__ params,
        float* __restrict__ out, float* __restrict__ accums) {
    __shared__ float sx[WPB][2][CHF];  // 73728 B: per-wave double buffers
    __shared__ float sU[512];          // Ur row-major, then Ui
    __shared__ float sg[48];           // 8 gates x {c,s,epr,epi,emr,emi}
    __shared__ float sv[256];          // per-wave pooled-v strips
    __shared__ float spart[8];

    const int t    = threadIdx.x;
    const int wid  = t >> 6;           // wave id (0..3)
    const int lane = t & 63;
    const int e    = lane >> 4;        // image within chunk (0..3)
    const int p    = lane & 15;        // pool cell == state row

    const size_t ibase = (size_t)blockIdx.x * EPB + (size_t)wid * IPW;

    // ---- per-lane staging source offsets (floats) for the 9 gload16
    int goff[9];
#pragma unroll
    for (int j = 0; j < 9; ++j) {
        int Lf  = j * 256 + lane * 4;
        int q   = Lf / 72;             // pair index 0..31
        int rem = Lf - q * 72;
        int rr  = rem / 12;            // row in cell 0..5
        int mm  = rem - rr * 12;       // 0,4,8
        int e2 = q >> 3, pr2 = (q >> 1) & 3, P2 = q & 1;
        goff[j] = e2 * 576 + (pr2 * 6 + rr) * 24 + P2 * 12 + mm;
    }

    // ---- prefetch chunk 0 into this wave's buffer 0 (swizzled source)
    {
        const float* xb = x + ibase * XPER;
        float* dst = &sx[wid][0][0];
#pragma unroll
        for (int j = 0; j < 9; ++j) gload16(xb + goff[j], dst + j * 256);
    }

    if (t < 8) {
        spart[t] = 0.0f;
        float phi   = params[t * 3 + 0];
        float theta = params[t * 3 + 1];
        float omega = params[t * 3 + 2];
        float apo = 0.5f * (phi + omega), amo = 0.5f * (phi - omega);
        sg[t * 6 + 0] = cosf(0.5f * theta);
        sg[t * 6 + 1] = sinf(0.5f * theta);
        sg[t * 6 + 2] = cosf(apo);           // epr (ep = e^{-i(phi+omega)/2})
        sg[t * 6 + 3] = -sinf(apo);          // epi
        sg[t * 6 + 4] = cosf(amo);           // emr (em = e^{+i(phi-omega)/2})
        sg[t * 6 + 5] = sinf(amo);           // emi
    }
    __syncthreads();

    // ---- fold circuit into U (lane j owns column j of M; state' = M state)
    if (t < 16) {
        const int j = t;
        float Mr[16], Mi[16];
#pragma unroll
        for (int i = 0; i < 16; ++i) { Mr[i] = (i == j) ? 1.0f : 0.0f; Mi[i] = 0.0f; }
#pragma unroll
        for (int l = 0; l < 2; ++l) {
#pragma unroll
            for (int w = 0; w < 4; ++w) {
                const int g = l * 4 + w;
                float c   = sg[g * 6 + 0], s   = sg[g * 6 + 1];
                float epr = sg[g * 6 + 2], epi = sg[g * 6 + 3];
                float emr = sg[g * 6 + 4], emi = sg[g * 6 + 5];
                float m00r =  epr * c, m00i =  epi * c;
                float m01r = -emr * s, m01i = -emi * s;
                float m10r =  emr * s, m10i = -emi * s;
                float m11r =  epr * c, m11i = -epi * c;
                const int mask = 1 << (3 - w);
#pragma unroll
                for (int i = 0; i < 16; ++i) {
                    if (i & mask) continue;
                    int i1 = i | mask;
                    float r0 = Mr[i],  q0 = Mi[i];
                    float r1 = Mr[i1], q1 = Mi[i1];
                    Mr[i]  = m00r * r0 - m00i * q0 + m01r * r1 - m01i * q1;
                    Mi[i]  = m00r * q0 + m00i * r0 + m01r * q1 + m01i * r1;
                    Mr[i1] = m10r * r0 - m10i * q0 + m11r * r1 - m11i * q1;
                    Mi[i1] = m10r * q0 + m10i * r0 + m11r * q1 + m11i * r1;
                }
            }
            const int rr = (l % 3) + 1;
#pragma unroll
            for (int w = 0; w < 4; ++w) {
                int tq = (w + rr) & 3;
                int cb = 3 - w, tb = 3 - tq;
#pragma unroll
                for (int i = 0; i < 16; ++i) {
                    int pi = i ^ (((i >> cb) & 1) << tb);
                    if (pi > i) {
                        float tr = Mr[i]; Mr[i] = Mr[pi]; Mr[pi] = tr;
                        float ti = Mi[i]; Mi[i] = Mi[pi]; Mi[pi] = ti;
                    }
                }
            }
        }
#pragma unroll
        for (int i = 0; i < 16; ++i) {
            sU[i * 16 + j]       = Mr[i];
            sU[256 + i * 16 + j] = Mi[i];
        }
    }
    __syncthreads();

    // ---- U row p -> registers (float4 LDS reads, once)
    float ur[16], ui[16];
    {
        const float4* u4 = (const float4*)(sU + p * 16);
        const float4* v4 = (const float4*)(sU + 256 + p * 16);
#pragma unroll
        for (int q = 0; q < 4; ++q) {
            float4 a = u4[q], b = v4[q];
            ur[4 * q + 0] = a.x; ur[4 * q + 1] = a.y; ur[4 * q + 2] = a.z; ur[4 * q + 3] = a.w;
            ui[4 * q + 0] = b.x; ui[4 * q + 1] = b.y; ui[4 * q + 2] = b.z; ui[4 * q + 3] = b.w;
        }
    }
    // ---- no more barriers until epilogue: waves run decoupled ----

    // ---- reader offsets: lane owns cell (e, prow, pc); side s of pair P
    const int prow = p >> 2, pc = p & 3;
    const int P = pc >> 1, s = pc & 1;
    const int qa = (e << 3) + (prow << 1) + P;
    const int rbase = qa * 72;
    const int r0 = qa % 6;
    int offF[6], offS[3];
#pragma unroll
    for (int k = 0; k < 6; ++k) {
        int rk = r0 + k; if (rk >= 6) rk -= 6;
        offF[k] = rbase + rk * 12 + (s ? 8 : 0);   // full f4 (own side)
    }
#pragma unroll
    for (int k = 0; k < 3; ++k) {
        int rk = r0 + 3 * s + k; if (rk >= 6) rk -= 6;
        offS[k] = rbase + rk * 12 + 4;             // split f4 (xy=L, zw=R)
    }

    // writer lane -> output channel (z_w lives at group-lane 1<<(3-w))
    int c = -1;
    if      (p == 8) c = 0;
    else if (p == 4) c = 1;
    else if (p == 2) c = 2;
    else if (p == 1) c = 3;

    float zbuf[NCH];
    float accz = 0.0f, accz2 = 0.0f;

#pragma unroll
    for (int ch = 0; ch < NCH; ++ch) {
        if (ch + 1 < NCH) {
            const float* xb = x + (ibase + (size_t)(ch + 1) * CHUNK) * XPER;
            float* dst = &sx[wid][(ch + 1) & 1][0];
#pragma unroll
            for (int j = 0; j < 9; ++j) gload16(xb + goff[j], dst + j * 256);
            asm volatile("s_waitcnt vmcnt(9)" ::: "memory");  // chunk ch landed
        } else {
            asm volatile("s_waitcnt vmcnt(0)" ::: "memory");
        }

        // ---- pool: 9 aligned b128 reads, pair-major layout
        const float* bb = &sx[wid][ch & 1][0];
        float accFull = 0.0f, accLs = 0.0f, accRs = 0.0f;
#pragma unroll
        for (int k = 0; k < 6; ++k) {
            float4 a = *(const float4*)(bb + offF[k]);
            accFull += a.x + a.y + a.z + a.w;
        }
#pragma unroll
        for (int k = 0; k < 3; ++k) {
            float4 a = *(const float4*)(bb + offS[k]);
            accLs += a.x + a.y;
            accRs += a.z + a.w;
        }
        float myL = s ? accLs : (accFull + accLs);
        float myR = s ? (accFull + accRs) : accRs;
        float send = s ? myL : myR;
        float recv = __shfl_xor(send, 1);          // pair-lane exchange
        float v = ((s ? myR : myL) + recv) * (1.0f / 36.0f);

        // ---- per-wave strip: write v, broadcast-read the image's 16 v's.
        sv[wid * 64 + e * 16 + p] = v;
        float vv[16];
        {
            const float4* vb = (const float4*)(sv + wid * 64 + e * 16);
#pragma unroll
            for (int q = 0; q < 4; ++q) {
                float4 a = vb[q];
                vv[4 * q + 0] = a.x; vv[4 * q + 1] = a.y;
                vv[4 * q + 2] = a.z; vv[4 * q + 3] = a.w;
            }
        }
        float n2 = 0.0f, sr = 0.0f, si = 0.0f;
#pragma unroll
        for (int j = 0; j < 16; ++j) {
            n2 = fmaf(vv[j], vv[j], n2);
            sr = fmaf(ur[j], vv[j], sr);
            si = fmaf(ui[j], vv[j], si);
        }
        float prob = (sr * sr + si * si) / n2;

        // ---- 16-pt Walsh-Hadamard across the 16-lane group
        float a = prob, o;
        o = __shfl_xor(a, 1); a = (t & 1) ? (o - a) : (a + o);
        o = __shfl_xor(a, 2); a = (t & 2) ? (o - a) : (a + o);
        o = __shfl_xor(a, 4); a = (t & 4) ? (o - a) : (a + o);
        o = __shfl_xor(a, 8); a = (t & 8) ? (o - a) : (a + o);

        zbuf[ch] = a;
        if (c >= 0) { accz += a; accz2 += a * a; }
    }

    // ---- epilogue: stores out of the loop (keeps vmcnt counts exact)
    if (c >= 0) {
#pragma unroll
        for (int ch = 0; ch < NCH; ++ch)
            out[(ibase + (size_t)ch * CHUNK + e) * 4 + c] = zbuf[ch];
        atomicAdd(&spart[c], accz);
        atomicAdd(&spart[4 + c], accz2);
    }
    __syncthreads();
    if (t < 8) atomicAdd(&accums[t], spart[t]);
}

// ---------------------------------------------------------------- K2
__global__ __launch_bounds__(256) void bn_apply(float* __restrict__ out,
                                                const float* __restrict__ accums,
                                                const float* __restrict__ gamma,
                                                const float* __restrict__ beta) {
    __shared__ float sc[8];
    const int t = threadIdx.x;
    if (t < 4) {
        float mu  = accums[t] * (1.0f / BATCH);
        float var = accums[4 + t] * (1.0f / BATCH) - mu * mu;
        float a = gamma[t] * rsqrtf(var + 1e-5f);
        sc[t]     = a;
        sc[4 + t] = beta[t] - mu * a;
    }
    __syncthreads();
    int i = blockIdx.x * 256 + t;   // one float4 (one image) each
    float4 z = ((float4*)out)[i];
    z.x = fmaf(z.x, sc[0], sc[4]);
    z.y = fmaf(z.y, sc[1], sc[5]);
    z.z = fmaf(z.z, sc[2], sc[6]);
    z.w = fmaf(z.w, sc[3], sc[7]);
    ((float4*)out)[i] = z;
}

extern "C" void kernel_launch(void* const* d_in, const int* in_sizes, int n_in,
                              void* d_out, int out_size, void* d_ws, size_t ws_size,
                              hipStream_t stream) {
    const float* x      = (const float*)d_in[0];
    const float* params = (const float*)d_in[1];
    const float* gamma  = (const float*)d_in[2];
    const float* beta   = (const float*)d_in[3];
    float* out = (float*)d_out;
    float* ws  = (float*)d_ws;

    hipMemsetAsync(ws, 0, 32, stream);   // zero BN accumulators
    hipLaunchKernelGGL(circuit_kernel, dim3(NBLK), dim3(256), 0, stream,
                       x, params, out, ws);
    hipLaunchKernelGGL(bn_apply, dim3(BATCH / 256), dim3(256), 0, stream,
                       out, ws, gamma, beta);
}

// Round 9
// 36.078 us; speedup vs baseline: 2.4650x; 1.1227x over previous
//
#include <hip/hip_runtime.h>
#include <math.h>

#define BATCH 65536
#define XPER  576               // 24*24 floats per image
#define NBLK  1024
#define WPB   4                 // waves per block
#define RPW   2                 // rounds per wave
#define IPR   8                 // images per round per wave
// block covers WPB*RPW*IPR = 64 images

// ws layout: slots[NBLK][8] partial sums (fully overwritten each launch;
// no zeroing, no global atomics, no memset node).

// ---------------------------------------------------------------- K1
// Direct-from-global pooling (no LDS staging). Lane = (image e, cell-pair q).
// 18 aligned float4 loads cover the pair strip (12 cols x 6 rows); lane's
// pooled cells (2q, 2q+1) are exactly its two matvec state rows.
__global__ __launch_bounds__(256, 3) void circuit_kernel(
        const float* __restrict__ x, const float* __restrict__ params,
        float* __restrict__ out, float* __restrict__ slots) {
    __shared__ float sUr[16 * 20];     // U real, row r at r*20 (padded)
    __shared__ float sUi[16 * 20];     // U imag
    __shared__ float sg[48];           // 8 gates x {c,s,epr,epi,emr,emi}
    __shared__ float sv[WPB][IPR * 20];// per-wave pooled-v strips (padded)
    __shared__ float spart[8];

    const int t    = threadIdx.x;
    const int wid  = t >> 6;           // wave id (0..3)
    const int lane = t & 63;
    const int e    = lane >> 3;        // image within round (0..7)
    const int q    = lane & 7;         // cell pair (covers cells 2q, 2q+1)
    const int pr   = q >> 1;           // cell row (0..3)
    const int P    = q & 1;            // pair column (0..1)

    if (t < 8) {
        spart[t] = 0.0f;
        float phi   = params[t * 3 + 0];
        float theta = params[t * 3 + 1];
        float omega = params[t * 3 + 2];
        float apo = 0.5f * (phi + omega), amo = 0.5f * (phi - omega);
        sg[t * 6 + 0] = cosf(0.5f * theta);
        sg[t * 6 + 1] = sinf(0.5f * theta);
        sg[t * 6 + 2] = cosf(apo);           // epr (ep = e^{-i(phi+omega)/2})
        sg[t * 6 + 3] = -sinf(apo);          // epi
        sg[t * 6 + 4] = cosf(amo);           // emr (em = e^{+i(phi-omega)/2})
        sg[t * 6 + 5] = sinf(amo);           // emi
    }
    __syncthreads();

    // ---- fold circuit into U (lane j owns column j of M; state' = M state)
    if (t < 16) {
        const int j = t;
        float Mr[16], Mi[16];
#pragma unroll
        for (int i = 0; i < 16; ++i) { Mr[i] = (i == j) ? 1.0f : 0.0f; Mi[i] = 0.0f; }
#pragma unroll
        for (int l = 0; l < 2; ++l) {
#pragma unroll
            for (int w = 0; w < 4; ++w) {
                const int g = l * 4 + w;
                float c   = sg[g * 6 + 0], s   = sg[g * 6 + 1];
                float epr = sg[g * 6 + 2], epi = sg[g * 6 + 3];
                float emr = sg[g * 6 + 4], emi = sg[g * 6 + 5];
                float m00r =  epr * c, m00i =  epi * c;
                float m01r = -emr * s, m01i = -emi * s;
                float m10r =  emr * s, m10i = -emi * s;
                float m11r =  epr * c, m11i = -epi * c;
                const int mask = 1 << (3 - w);
#pragma unroll
                for (int i = 0; i < 16; ++i) {
                    if (i & mask) continue;
                    int i1 = i | mask;
                    float r0 = Mr[i],  q0 = Mi[i];
                    float r1 = Mr[i1], q1 = Mi[i1];
                    Mr[i]  = m00r * r0 - m00i * q0 + m01r * r1 - m01i * q1;
                    Mi[i]  = m00r * q0 + m00i * r0 + m01r * q1 + m01i * r1;
                    Mr[i1] = m10r * r0 - m10i * q0 + m11r * r1 - m11i * q1;
                    Mi[i1] = m10r * q0 + m10i * r0 + m11r * q1 + m11i * r1;
                }
            }
            const int rr = (l % 3) + 1;
#pragma unroll
            for (int w = 0; w < 4; ++w) {
                int tq = (w + rr) & 3;
                int cb = 3 - w, tb = 3 - tq;
#pragma unroll
                for (int i = 0; i < 16; ++i) {
                    int pi = i ^ (((i >> cb) & 1) << tb);
                    if (pi > i) {
                        float tr = Mr[i]; Mr[i] = Mr[pi]; Mr[pi] = tr;
                        float ti = Mi[i]; Mi[i] = Mi[pi]; Mi[pi] = ti;
                    }
                }
            }
        }
#pragma unroll
        for (int i = 0; i < 16; ++i) {
            sUr[i * 20 + j] = Mr[i];
            sUi[i * 20 + j] = Mi[i];
        }
    }
    __syncthreads();

    // ---- hoist this lane's two U rows (2q, 2q+1) into registers
    float u0r[16], u0i[16], u1r[16], u1i[16];
    {
        const float4* r0 = (const float4*)(sUr + (2 * q) * 20);
        const float4* r1 = (const float4*)(sUr + (2 * q + 1) * 20);
        const float4* i0 = (const float4*)(sUi + (2 * q) * 20);
        const float4* i1 = (const float4*)(sUi + (2 * q + 1) * 20);
#pragma unroll
        for (int m = 0; m < 4; ++m) {
            float4 a = r0[m], b = r1[m], cc = i0[m], d = i1[m];
            u0r[4*m+0]=a.x; u0r[4*m+1]=a.y; u0r[4*m+2]=a.z; u0r[4*m+3]=a.w;
            u1r[4*m+0]=b.x; u1r[4*m+1]=b.y; u1r[4*m+2]=b.z; u1r[4*m+3]=b.w;
            u0i[4*m+0]=cc.x; u0i[4*m+1]=cc.y; u0i[4*m+2]=cc.z; u0i[4*m+3]=cc.w;
            u1i[4*m+0]=d.x; u1i[4*m+1]=d.y; u1i[4*m+2]=d.z; u1i[4*m+3]=d.w;
        }
    }

    // writer lane -> channel: z0@q=4, z1@q=2, z2@q=1, z3@q=0
    int c = -1;
    if      (q == 4) c = 0;
    else if (q == 2) c = 1;
    else if (q == 1) c = 2;
    else if (q == 0) c = 3;

    const int cbase = pr * 144 + P * 12;   // strip base within image (floats)
    float accz = 0.0f, accz2 = 0.0f;

#pragma unroll
    for (int rd = 0; rd < RPW; ++rd) {
        const size_t img = (size_t)blockIdx.x * 64 + wid * 16 + rd * 8 + e;
        const float* ip = x + img * XPER + cbase;

        // ---- pool the 12x6 strip: 18 aligned float4 loads, two cell sums
        float L = 0.0f, R = 0.0f;
#pragma unroll
        for (int r = 0; r < 6; ++r) {
            float4 a = *(const float4*)(ip + r * 24);
            float4 b = *(const float4*)(ip + r * 24 + 4);
            float4 d = *(const float4*)(ip + r * 24 + 8);
            L += a.x + a.y + a.z + a.w + b.x + b.y;
            R += b.z + b.w + d.x + d.y + d.z + d.w;
        }
        float vL = L * (1.0f / 36.0f), vR = R * (1.0f / 36.0f);

        // ---- redistribute via per-wave padded strip (write b64, 4x b128
        // broadcast reads; wave-private + DS in-order => no barrier)
        *(float2*)(&sv[wid][e * 20 + 2 * q]) = make_float2(vL, vR);
        float vv[16];
        {
            const float4* vb = (const float4*)(&sv[wid][e * 20]);
#pragma unroll
            for (int m = 0; m < 4; ++m) {
                float4 a = vb[m];
                vv[4*m+0]=a.x; vv[4*m+1]=a.y; vv[4*m+2]=a.z; vv[4*m+3]=a.w;
            }
        }

        // ---- matvec for state rows 2q, 2q+1 (input state real)
        float n2 = 0.0f, sr0 = 0.0f, si0 = 0.0f, sr1 = 0.0f, si1 = 0.0f;
#pragma unroll
        for (int j = 0; j < 16; ++j) {
            float vj = vv[j];
            n2  = fmaf(vj, vj, n2);
            sr0 = fmaf(u0r[j], vj, sr0); si0 = fmaf(u0i[j], vj, si0);
            sr1 = fmaf(u1r[j], vj, sr1); si1 = fmaf(u1i[j], vj, si1);
        }
        float inv = 1.0f / n2;
        float p0 = (sr0 * sr0 + si0 * si0) * inv;
        float p1 = (sr1 * sr1 + si1 * si1) * inv;

        // ---- WHT: bit0 in-register, bits 1..3 via 8-lane butterflies
        float u = p0 + p1, d = p0 - p1, o;
        o = __shfl_xor(u, 1); u = (q & 1) ? (o - u) : (u + o);
        o = __shfl_xor(u, 2); u = (q & 2) ? (o - u) : (u + o);
        o = __shfl_xor(u, 4); u = (q & 4) ? (o - u) : (u + o);
        d += __shfl_xor(d, 1);
        d += __shfl_xor(d, 2);
        d += __shfl_xor(d, 4);
        // lane q=4: z0; q=2: z1; q=1: z2; q=0: z3 (=sum of d)

        if (c >= 0) {
            float z = (q == 0) ? d : u;
            out[img * 4 + c] = z;        // raw z, normalized by K2
            accz  += z;
            accz2 += z * z;
        }
    }

    // ---- per-block partials -> private slot (no global atomics, no memset)
    if (c >= 0) {
        atomicAdd(&spart[c], accz);
        atomicAdd(&spart[4 + c], accz2);
    }
    __syncthreads();
    if (t < 8) slots[blockIdx.x * 8 + t] = spart[t];
}

// ---------------------------------------------------------------- K2
// Reduce per-block slots + finalize BN stats + apply affine in place.
__global__ __launch_bounds__(256) void bn_apply(float* __restrict__ out,
                                                const float* __restrict__ slots,
                                                const float* __restrict__ gamma,
                                                const float* __restrict__ beta) {
    __shared__ float red[256];
    __shared__ float sc[8];
    const int t = threadIdx.x;
    const int ch = t & 7, g = t >> 3;      // g in 0..31
    float s = 0.0f;
#pragma unroll
    for (int k = 0; k < NBLK / 32; ++k)
        s += slots[(size_t)(g + 32 * k) * 8 + ch];
    red[t] = s;
    __syncthreads();
#pragma unroll
    for (int stp = 128; stp >= 8; stp >>= 1) {
        if (t < stp) red[t] += red[t + stp];
        __syncthreads();
    }
    if (t < 4) {
        float mu  = red[t] * (1.0f / BATCH);
        float var = red[4 + t] * (1.0f / BATCH) - mu * mu;
        float a = gamma[t] * rsqrtf(var + 1e-5f);
        sc[t]     = a;
        sc[4 + t] = beta[t] - mu * a;
    }
    __syncthreads();
    int i = blockIdx.x * 256 + t;   // one float4 (one image) each
    float4 z = ((float4*)out)[i];
    z.x = fmaf(z.x, sc[0], sc[4]);
    z.y = fmaf(z.y, sc[1], sc[5]);
    z.z = fmaf(z.z, sc[2], sc[6]);
    z.w = fmaf(z.w, sc[3], sc[7]);
    ((float4*)out)[i] = z;
}

extern "C" void kernel_launch(void* const* d_in, const int* in_sizes, int n_in,
                              void* d_out, int out_size, void* d_ws, size_t ws_size,
                              hipStream_t stream) {
    const float* x      = (const float*)d_in[0];
    const float* params = (const float*)d_in[1];
    const float* gamma  = (const float*)d_in[2];
    const float* beta   = (const float*)d_in[3];
    float* out = (float*)d_out;
    float* ws  = (float*)d_ws;

    hipLaunchKernelGGL(circuit_kernel, dim3(NBLK), dim3(256), 0, stream,
                       x, params, out, ws);
    hipLaunchKernelGGL(bn_apply, dim3(BATCH / 256), dim3(256), 0, stream,
                       out, ws, gamma, beta);
}